// Round 8
// baseline (155.957 us; speedup 1.0000x reference)
//
#include <hip/hip_runtime.h>

#define NQv 20000
#define NSv 8192
#define Cv  112
#define CLSv 20
#define INFF 3.4e38f
#define JINF 0x7fffffff

#define GC 16
#define NCELL 4096
#define CELLH 8.0f
#define INVH 0.125f

#define POOLB 32
#define PT 1024
#define PNW (POOLB * PT / 64)       // 512 waves across pool blocks

#define MQ 32                       // queries per fused block
#define MB (NQv / MQ)               // 625 fused blocks
#define MT 1024                     // 16 waves: 32 query-groups of 32 lanes each
// ws floats: [0,3616) pool partials TRANSPOSED [113][32]; u16 start[4098] @3616; pts4 @5668
#define WS_START 3616
#define WS_PTS4  5668
#define WS_W1TH  38440              // u16 [112][224] bf16-hi of W1^T
#define WS_W1TL  50984              // u16 [112][224] bf16-lo
#define WS_W2TH  63528              // u16 [112][128] (K zero-padded)
#define WS_W2TL  70696
#define WS_WCT   77864              // f32 [20][112] Wc^T

typedef __attribute__((ext_vector_type(8))) short bf16x8;   // 8 bf16 = 4 VGPRs
typedef __attribute__((ext_vector_type(4))) float f32x4;
typedef unsigned short us;
typedef unsigned long long u64;

__device__ __forceinline__ float bf2f(us u) {
    union { unsigned int i; float f; } v; v.i = ((unsigned int)u) << 16; return v.f;
}
__device__ __forceinline__ us f2bf(float f) {
    union { float f; unsigned int i; } v; v.f = f;
    unsigned int r = v.i + 0x7fffu + ((v.i >> 16) & 1u);
    return (us)(r >> 16);
}
__device__ __forceinline__ void split(float v, us& h, us& l) {
    h = f2bf(v); l = f2bf(v - bf2f(h));
}

// sortable-u64 key: ascending u64 order == lex-(e asc, j asc)
__device__ __forceinline__ u64 mkkey(float e, int j) {
    union { float f; unsigned int i; } v; v.f = e;
    unsigned int ue = v.i ^ ((unsigned int)((int)v.i >> 31) | 0x80000000u);
    return ((u64)ue << 32) | (unsigned int)j;
}
__device__ __forceinline__ float keyval(u64 k) {
    unsigned int ue = (unsigned int)(k >> 32);
    unsigned int u = ue ^ ((unsigned int)((int)(~ue) >> 31) | 0x80000000u);
    union { unsigned int i; float f; } v; v.i = u; return v.f;
}
__device__ __forceinline__ u64 umin64(u64 a, u64 b) { return a < b ? a : b; }
__device__ __forceinline__ u64 umax64(u64 a, u64 b) { return a > b ? a : b; }

// ---- prep: pool (0..31) + grid build (32) + weight tables (33,34); 1024 threads
__global__ __launch_bounds__(PT) void k_prep(const float* __restrict__ cs,
                                             const float* __restrict__ fs7,
                                             const float* __restrict__ wat,
                                             const float* __restrict__ W1,
                                             const float* __restrict__ W2,
                                             const float* __restrict__ Wc,
                                             float* __restrict__ ws) {
    int b = blockIdx.x, tid = threadIdx.x;

    if (b == POOLB + 1) {           // W1^T bf16 hi/lo tables
        us* w1h = (us*)(ws + WS_W1TH);
        us* w1l = (us*)(ws + WS_W1TL);
        for (int idx = tid; idx < Cv * 224; idx += PT) {
            int c = idx / 224, k = idx - c * 224;
            us h, l; split(W1[k * Cv + c], h, l);
            w1h[c * 224 + k] = h; w1l[c * 224 + k] = l;
        }
        return;
    }
    if (b == POOLB + 2) {           // W2^T (K padded to 128) + Wc^T
        us* w2h = (us*)(ws + WS_W2TH);
        us* w2l = (us*)(ws + WS_W2TL);
        for (int idx = tid; idx < Cv * 128; idx += PT) {
            int c = idx >> 7, k = idx & 127;
            float v = (k < Cv) ? W2[k * Cv + c] : 0.f;
            us h, l; split(v, h, l);
            w2h[c * 128 + k] = h; w2l[c * 128 + k] = l;
        }
        float* wct = ws + WS_WCT;
        for (int idx = tid; idx < CLSv * Cv; idx += PT) {
            int cls = idx / Cv, k = idx - cls * Cv;
            wct[cls * Cv + k] = Wc[k * CLSv + cls];
        }
        return;
    }
    if (b == POOLB) {               // grid build: reg-cached coords, 2-barrier scan
        __shared__ int cnt[NCELL];
        __shared__ int wsum[PT / 64];
        us* startg = (us*)(ws + WS_START);
        float4* pts4 = (float4*)(ws + WS_PTS4);
        int lane = tid & 63, wv = tid >> 6;
        for (int i = tid; i < NCELL; i += PT) cnt[i] = 0;
        __syncthreads();
        float xx[8], yy[8], zz[8]; int cid[8]; int pp[8];
        #pragma unroll
        for (int k = 0; k < NSv / PT; ++k) {
            int p = k * PT + tid;
            pp[k] = p;
            xx[k] = cs[3 * p]; yy[k] = cs[3 * p + 1]; zz[k] = cs[3 * p + 2];
            int cx = (int)(xx[k] * INVH), cy = (int)(yy[k] * INVH), cz = (int)(zz[k] * INVH);
            cx = cx > 15 ? 15 : cx; cy = cy > 15 ? 15 : cy; cz = cz > 15 ? 15 : cz;
            cid[k] = (cz * GC + cy) * GC + cx;
            atomicAdd(&cnt[cid[k]], 1);
        }
        __syncthreads();
        int base = tid * 4;
        int c0 = cnt[base], c1 = cnt[base + 1], c2 = cnt[base + 2], c3 = cnt[base + 3];
        int local = c0 + c1 + c2 + c3;
        int inc = local;                           // wave inclusive scan
        #pragma unroll
        for (int off = 1; off < 64; off <<= 1) {
            int v = __shfl_up(inc, off, 64);
            if (lane >= off) inc += v;
        }
        if (lane == 63) wsum[wv] = inc;
        __syncthreads();
        if (tid < PT / 64) {                       // scan 16 wave totals (wave 0)
            int v = wsum[tid];
            #pragma unroll
            for (int off = 1; off < 16; off <<= 1) {
                int o = __shfl_up(v, off, 64);
                if (tid >= off) v += o;
            }
            wsum[tid] = v;
        }
        __syncthreads();
        int wbase = (wv == 0) ? 0 : wsum[wv - 1];
        int run = wbase + inc - local;             // exclusive prefix for this thread
        startg[base] = (us)run;     cnt[base] = run;     run += c0;
        startg[base + 1] = (us)run; cnt[base + 1] = run; run += c1;
        startg[base + 2] = (us)run; cnt[base + 2] = run; run += c2;
        startg[base + 3] = (us)run; cnt[base + 3] = run;
        if (tid == 0) startg[NCELL] = (us)NSv;
        __syncthreads();
        #pragma unroll
        for (int k = 0; k < NSv / PT; ++k) {
            int slot = atomicAdd(&cnt[cid[k]], 1);
            pts4[slot] = make_float4(-2.f * xx[k], -2.f * yy[k], -2.f * zz[k], (float)pp[k]);
        }
        return;
    }

    // pool partials: 512 waves total, 16 rows each; TRANSPOSED store [ch][b]
    __shared__ float red[PT / 64][Cv + 1];
    int gtid = b * PT + tid;
    int wid = gtid >> 6, lw = tid >> 6, lane = gtid & 63, l2 = lane * 2;
    float2 wa = make_float2(0.f, 0.f);
    if (lane < 56) wa = *(const float2*)(wat + l2);
    float gx = 0.f, gy = 0.f, z = 0.f;
    for (int g = 0; g < 2; ++g) {
        float2 f[8]; float part[8];
        #pragma unroll
        for (int u = 0; u < 8; ++u) {
            int i = wid + (g * 8 + u) * PNW;
            f[u] = (lane < 56) ? *(const float2*)(fs7 + i * Cv + l2) : make_float2(0.f, 0.f);
            part[u] = f[u].x * wa.x + f[u].y * wa.y;
        }
        #pragma unroll
        for (int off = 32; off; off >>= 1)
            #pragma unroll
            for (int u = 0; u < 8; ++u) part[u] += __shfl_xor(part[u], off, 64);
        #pragma unroll
        for (int u = 0; u < 8; ++u) {
            float p = __expf(part[u]);
            gx = fmaf(p, f[u].x, gx); gy = fmaf(p, f[u].y, gy); z += p;
        }
    }
    if (lane < 56) { red[lw][l2] = gx; red[lw][l2 + 1] = gy; }
    if (lane == 0) red[lw][Cv] = z;
    __syncthreads();
    if (tid < Cv + 1) {
        float s = 0.f;
        #pragma unroll
        for (int i = 0; i < PT / 64; ++i) s += red[i][tid];
        ws[tid * POOLB + b] = s;                   // transposed: row=channel, col=block
    }
}

// single-point lex-(e, idx) top-3 insert; canonical FMA chain for e
__device__ __forceinline__ void ins_pt(float4 P, float qx, float qy, float qz,
                                       float& E0, float& E1, float& E2,
                                       int& J0, int& J1, int& J2) {
    float x = -0.5f * P.x, y = -0.5f * P.y, z = -0.5f * P.z;
    float s2 = fmaf(x, x, fmaf(y, y, z * z));
    float e = fmaf(qx, P.x, fmaf(qy, P.y, fmaf(qz, P.z, s2)));
    int j = (int)P.w;
    bool lt2 = (e < E2) || (e == E2 && j < J2);
    if (lt2) {
        bool lt1 = (e < E1) || (e == E1 && j < J1);
        bool lt0 = (e < E0) || (e == E0 && j < J0);
        E2 = lt1 ? E1 : e;              J2 = lt1 ? J1 : j;
        E1 = lt0 ? E0 : (lt1 ? e : E1); J1 = lt0 ? J0 : (lt1 ? j : J1);
        if (lt0) { E0 = e; J0 = j; }
    }
}

// 2-wide point stream: both loads issue before the insert chain; order k,k+1 kept
__device__ __forceinline__ void scan_run(const float4* __restrict__ pts4,
                                         int a, int b, float qx, float qy, float qz,
                                         float& E0, float& E1, float& E2,
                                         int& J0, int& J1, int& J2) {
    int k = a;
    for (; k + 2 <= b; k += 2) {
        float4 P0 = pts4[k];
        float4 P1 = pts4[k + 1];
        ins_pt(P0, qx, qy, qz, E0, E1, E2, J0, J1, J2);
        ins_pt(P1, qx, qy, qz, E0, E1, E2, J0, J1, J2);
    }
    if (k < b) {
        float4 P0 = pts4[k];
        ins_pt(P0, qx, qy, qz, E0, E1, E2, J0, J1, J2);
    }
}

// ---- fused: 32-lane-group kNN search + MFMA MLP. 1024 threads, 32 q/block.
// 32 lanes per query halves every per-lane serial chain vs 16-lane groups.
__global__ __launch_bounds__(MT, 8) void k_fused(
        const float* __restrict__ cq,
        const float* __restrict__ x7, const float* __restrict__ fs,
        const float* __restrict__ gma, const float* __restrict__ bta,
        const float* __restrict__ bc, const float* __restrict__ ws,
        float* __restrict__ out) {
    __shared__ __align__(16) us vb[2 * MQ * 232];   // [hi | lo], h2f aliases after GEMM1
    __shared__ __align__(16) us hbh[MQ * 136];      // h1 bf16-hi, K padded to 128
    __shared__ __align__(16) us hbl[MQ * 136];
    __shared__ float gate[Cv];

    us* vbh = vb;
    us* vbl = vb + MQ * 232;
    float* h2f = (float*)vb;                        // 32*116 f32 = 14848 B, fits

    const us* __restrict__ startg = (const us*)(ws + WS_START);
    const float4* __restrict__ pts4 = (const float4*)(ws + WS_PTS4);

    int tid = threadIdx.x;
    int q0 = blockIdx.x * MQ;
    int sub = tid & 31;                          // lane within the 32-lane query group
    int qq  = tid >> 5;                          // 0..31: this thread's query
    int q   = q0 + qq;

    // x7 prefetch: 8 columns per lane (sub<14), hides HBM latency under search
    float4 px[2];
    if (sub < 14) {
        const float4* xr = (const float4*)(x7 + q * Cv + sub * 8);
        px[0] = xr[0]; px[1] = xr[1];
    }

    if (tid < Cv) {                              // gate = sigmoid(pooled mean), coalesced
        float st = 0.f, zt = 0.f;
        const float* pr = ws + tid * POOLB;
        const float* zr = ws + Cv * POOLB;
        #pragma unroll
        for (int b = 0; b < POOLB; ++b) { st += pr[b]; zt += zr[b]; }
        gate[tid] = 1.0f / (1.0f + __expf(-(st / zt)));
    }
    if (tid < MQ * 16) {                         // zero h1 K-pad (k=112..127)
        int zq = tid >> 4, kk = Cv + (tid & 15);
        hbh[zq * 136 + kk] = 0; hbl[zq * 136 + kk] = 0;
    }
    __syncthreads();                             // gate + K-pad visible to everyone

    // ---- search phase: 32 groups of 32 lanes, one query each
    u64 K0 = ~0ull, K1 = ~0ull, K2 = ~0ull;
    {
        float qx = cq[3 * q], qy = cq[3 * q + 1], qz = cq[3 * q + 2];
        float q2 = fmaf(qx, qx, fmaf(qy, qy, qz * qz));
        int cx = (int)(qx * INVH), cy = (int)(qy * INVH), cz = (int)(qz * INVH);
        cx = cx > 15 ? 15 : cx; cy = cy > 15 ? 15 : cy; cz = cz > 15 ? 15 : cz;
        float E0 = INFF, E1 = INFF, E2 = INFF;
        int   J0 = JINF, J1 = JINF, J2 = JINF;

        if (sub < 27) {                          // 3x3x3 core: one cell per lane
            int dz = sub / 9 - 1, dy = (sub / 3) % 3 - 1, dx = sub % 3 - 1;
            int xc = cx + dx, yc = cy + dy, zc = cz + dz;
            if ((unsigned)xc < 16u && (unsigned)yc < 16u && (unsigned)zc < 16u) {
                int ccell = (zc * GC + yc) * GC + xc;
                scan_run(pts4, startg[ccell], startg[ccell + 1], qx, qy, qz,
                         E0, E1, E2, J0, J1, J2);
            }
        }

        bool done = false;
        for (int s = 2; ; ++s) {
            if (!done) {                         // 32-lane merge butterfly (5 steps)
                K0 = mkkey(E0, J0); K1 = mkkey(E1, J1); K2 = mkkey(E2, J2);
                #pragma unroll
                for (int off = 1; off < 32; off <<= 1) {
                    u64 b0 = __shfl_xor(K0, off, 64);
                    u64 b1 = __shfl_xor(K1, off, 64);
                    u64 b2 = __shfl_xor(K2, off, 64);
                    u64 xx = umax64(K0, b0), yy = umin64(K1, b1);
                    u64 zz = umax64(K1, b1), uu = umin64(K2, b2);
                    K0 = umin64(K0, b0);
                    u64 n1 = umin64(xx, yy);
                    K2 = umin64(umin64(umax64(xx, yy), zz), uu);
                    K1 = n1;
                }
            }
            if (s > 15) break;
            if (!done) {
                int r = s - 1;
                int xl = cx - r > 0 ? cx - r : 0, xh = cx + r < 15 ? cx + r : 15;
                int yl = cy - r > 0 ? cy - r : 0, yh = cy + r < 15 ? cy + r : 15;
                int zl = cz - r > 0 ? cz - r : 0, zh = cz + r < 15 ? cz + r : 15;
                float fx = INFF, fy = INFF, fz = INFF;
                if (xl > 0)  fx = qx - xl * CELLH;
                if (xh < 15) fx = fminf(fx, (xh + 1) * CELLH - qx);
                if (yl > 0)  fy = qy - yl * CELLH;
                if (yh < 15) fy = fminf(fy, (yh + 1) * CELLH - qy);
                if (zl > 0)  fz = qz - zl * CELLH;
                if (zh < 15) fz = fminf(fz, (zh + 1) * CELLH - qz);
                float dmin = fminf(fx, fminf(fy, fz));
                float t2 = keyval(K2);
                if (dmin * dmin > t2 + q2 + 0.5f) {
                    done = true;
                } else if (s == 2) {             // specialized: compile-time divides
                    for (int idx = sub; idx < 125; idx += 32) {
                        int dz = idx / 25 - 2;
                        int rem = idx - (dz + 2) * 25;
                        int dy = rem / 5 - 2;
                        int dx = rem - (dy + 2) * 5 - 2;
                        int ax = dx < 0 ? -dx : dx, ay = dy < 0 ? -dy : dy, az = dz < 0 ? -dz : dz;
                        if (ax != 2 && ay != 2 && az != 2) continue;
                        int xc = cx + dx, yc = cy + dy, zc = cz + dz;
                        if ((unsigned)xc > 15u || (unsigned)yc > 15u || (unsigned)zc > 15u) continue;
                        int ccell = (zc * GC + yc) * GC + xc;
                        scan_run(pts4, startg[ccell], startg[ccell + 1], qx, qy, qz,
                                 E0, E1, E2, J0, J1, J2);
                    }
                } else {
                    int side = 2 * s + 1, s2n = side * side, tot = s2n * side;
                    for (int idx = sub; idx < tot; idx += 32) {
                        int dz = idx / s2n - s;
                        int rem = idx - (dz + s) * s2n;
                        int dy = rem / side - s;
                        int dx = rem - (dy + s) * side - s;
                        int ax = dx < 0 ? -dx : dx, ay = dy < 0 ? -dy : dy, az = dz < 0 ? -dz : dz;
                        if (ax != s && ay != s && az != s) continue;
                        int xc = cx + dx, yc = cy + dy, zc = cz + dz;
                        if ((unsigned)xc > 15u || (unsigned)yc > 15u || (unsigned)zc > 15u) continue;
                        int ccell = (zc * GC + yc) * GC + xc;
                        scan_run(pts4, startg[ccell], startg[ccell + 1], qx, qy, qz,
                                 E0, E1, E2, J0, J1, J2);
                    }
                }
            }
            if (__all(done)) break;
        }
    }

    // ---- group-local V build: 8 columns per lane (lanes 0..27 of each group)
    {
        unsigned int A0 = (unsigned int)K0;
        unsigned int A1 = (unsigned int)K1;
        unsigned int A2 = (unsigned int)K2;
        if (A0 >= NSv) A0 = 0;
        if (A1 >= NSv) A1 = 0;
        if (A2 >= NSv) A2 = 0;
        if (sub < 14) {                          // gated x7: cols sub*8..+8
            int k0 = sub * 8;
            const float4* g4 = (const float4*)(gate + k0);
            float vals[8];
            #pragma unroll
            for (int i = 0; i < 2; ++i) {
                float4 v = px[i], g = g4[i];
                vals[i * 4]     = v.x * g.x;
                vals[i * 4 + 1] = v.y * g.y;
                vals[i * 4 + 2] = v.z * g.z;
                vals[i * 4 + 3] = v.w * g.w;
            }
            #pragma unroll
            for (int i = 0; i < 8; ++i) {
                us h, l; split(vals[i], h, l);
                vbh[qq * 232 + k0 + i] = h;
                vbl[qq * 232 + k0 + i] = l;
            }
        } else if (sub < 28) {                   // matched: cols 112+kk..+8
            float e0 = keyval(K0), e1 = keyval(K1), e2 = keyval(K2);
            float w1v = __expf(e0 - e1);
            float w2v = __expf(e0 - e2);
            float iw  = 1.0f / (1.0f + w1v + w2v);
            float w0 = iw, w1 = w1v * iw, w2 = w2v * iw;
            int kk = (sub - 14) * 8;
            const float4* r0 = (const float4*)(fs + A0 * Cv + kk);
            const float4* r1 = (const float4*)(fs + A1 * Cv + kk);
            const float4* r2 = (const float4*)(fs + A2 * Cv + kk);
            float vals[8];
            #pragma unroll
            for (int i = 0; i < 2; ++i) {
                float4 a = r0[i], b = r1[i], c = r2[i];
                vals[i * 4]     = w0 * a.x + w1 * b.x + w2 * c.x;
                vals[i * 4 + 1] = w0 * a.y + w1 * b.y + w2 * c.y;
                vals[i * 4 + 2] = w0 * a.z + w1 * b.z + w2 * c.z;
                vals[i * 4 + 3] = w0 * a.w + w1 * b.w + w2 * c.w;
            }
            int k0 = Cv + kk;
            #pragma unroll
            for (int i = 0; i < 8; ++i) {
                us h, l; split(vals[i], h, l);
                vbh[qq * 232 + k0 + i] = h;
                vbl[qq * 232 + k0 + i] = l;
            }
        }
    }
    __syncthreads();

    int w = tid >> 6, lane = tid & 63, quad = lane >> 4, l16 = lane & 15;
    int ct = (w < 14) ? (w >> 1) : 0;            // channel tile 0..6
    int mt = (w & 1) * 16;                       // M-tile row offset 0 or 16
    int cc = ct * 16 + l16;

    // GEMM1: h1 = V @ W1  (K=224, 7 ksteps, 3 MFMA terms; one (ct,mt) per wave)
    if (w < 14) {
        f32x4 acc = {0.f, 0.f, 0.f, 0.f};
        const us* w1h = (const us*)(ws + WS_W1TH) + cc * 224;
        const us* w1l = (const us*)(ws + WS_W1TL) + cc * 224;
        #pragma unroll
        for (int ks = 0; ks < 7; ++ks) {
            int ko = ks * 32 + quad * 8;
            bf16x8 bh = *(const bf16x8*)(w1h + ko);
            bf16x8 bl = *(const bf16x8*)(w1l + ko);
            bf16x8 ah = *(const bf16x8*)(vbh + (mt + l16) * 232 + ko);
            bf16x8 al = *(const bf16x8*)(vbl + (mt + l16) * 232 + ko);
            acc = __builtin_amdgcn_mfma_f32_16x16x32_bf16(ah, bh, acc, 0, 0, 0);
            acc = __builtin_amdgcn_mfma_f32_16x16x32_bf16(al, bh, acc, 0, 0, 0);
            acc = __builtin_amdgcn_mfma_f32_16x16x32_bf16(ah, bl, acc, 0, 0, 0);
        }
        float g = gma[cc], bb = bta[cc];
        #pragma unroll
        for (int r = 0; r < 4; ++r) {            // D row = mt + quad*4+r, col = cc
            int dq = mt + quad * 4 + r;
            float h = fmaf(acc[r], g, bb); h = h > 0.f ? h : 0.f;
            us hh, ll; split(h, hh, ll);
            hbh[dq * 136 + cc] = hh; hbl[dq * 136 + cc] = ll;
        }
    }
    __syncthreads();

    // GEMM2: h2 = h1 @ W2  (K=128 padded, 4 ksteps); h2f overwrites dead V region
    if (w < 14) {
        f32x4 acc = {0.f, 0.f, 0.f, 0.f};
        const us* w2h = (const us*)(ws + WS_W2TH) + cc * 128;
        const us* w2l = (const us*)(ws + WS_W2TL) + cc * 128;
        #pragma unroll
        for (int ks = 0; ks < 4; ++ks) {
            int ko = ks * 32 + quad * 8;
            bf16x8 bh = *(const bf16x8*)(w2h + ko);
            bf16x8 bl = *(const bf16x8*)(w2l + ko);
            bf16x8 ah = *(const bf16x8*)(hbh + (mt + l16) * 136 + ko);
            bf16x8 al = *(const bf16x8*)(hbl + (mt + l16) * 136 + ko);
            acc = __builtin_amdgcn_mfma_f32_16x16x32_bf16(ah, bh, acc, 0, 0, 0);
            acc = __builtin_amdgcn_mfma_f32_16x16x32_bf16(al, bh, acc, 0, 0, 0);
            acc = __builtin_amdgcn_mfma_f32_16x16x32_bf16(ah, bl, acc, 0, 0, 0);
        }
        #pragma unroll
        for (int r = 0; r < 4; ++r) {
            int dq = mt + quad * 4 + r;
            h2f[dq * 116 + cc] = acc[r];
        }
    }
    __syncthreads();

    // classifier: out = h2 @ Wc + bc (f32 VALU, WcT rows contiguous)
    for (int it = tid; it < MQ * CLSv; it += MT) {
        int cls = it % CLSv, oq = it / CLSv;
        const float4* wr = (const float4*)(ws + WS_WCT + cls * Cv);
        const float4* hr = (const float4*)(h2f + oq * 116);
        float a = bc[cls];
        #pragma unroll 7
        for (int i = 0; i < 28; ++i) {
            float4 h = hr[i], v = wr[i];
            a = fmaf(h.x, v.x, fmaf(h.y, v.y, fmaf(h.z, v.z, fmaf(h.w, v.w, a))));
        }
        out[(q0 + oq) * CLSv + cls] = a;
    }
}

extern "C" void kernel_launch(void* const* d_in, const int* in_sizes, int n_in,
                              void* d_out, int out_size, void* d_ws, size_t ws_size,
                              hipStream_t stream) {
    const float* cq  = (const float*)d_in[0];
    const float* cs  = (const float*)d_in[1];
    const float* x7  = (const float*)d_in[2];
    const float* fs7 = (const float*)d_in[3];
    const float* fs  = (const float*)d_in[4];
    const float* wat = (const float*)d_in[5];
    const float* W1  = (const float*)d_in[6];
    const float* gma = (const float*)d_in[7];
    const float* bta = (const float*)d_in[8];
    const float* W2  = (const float*)d_in[9];
    const float* Wc  = (const float*)d_in[10];
    const float* bc  = (const float*)d_in[11];
    float* ws  = (float*)d_ws;
    float* out = (float*)d_out;

    k_prep<<<POOLB + 3, PT, 0, stream>>>(cs, fs7, wat, W1, W2, Wc, ws);
    k_fused<<<MB, MT, 0, stream>>>(cq, x7, fs, gma, bta, bc, ws, out);
}

// Round 10
// 141.117 us; speedup vs baseline: 1.1052x; 1.1052x over previous
//
#include <hip/hip_runtime.h>

#define NQv 20000
#define NSv 8192
#define Cv  112
#define CLSv 20
#define INFF 3.4e38f
#define JINF 0x7fffffff

#define GC 16
#define NCELL 4096
#define CELLH 8.0f
#define INVH 0.125f

#define POOLB 32
#define PT 1024
#define PNW (POOLB * PT / 64)       // 512 waves across pool blocks

#define MQ 32                       // queries per fused block
#define MB (NQv / MQ)               // 625 fused blocks
#define MT 512                      // 8 waves: 32 query-groups of 16 lanes each
// ws floats: [0,3616) pool partials TRANSPOSED [113][32]; u16 start[4098] @3616; pts4 @5668
#define WS_START 3616
#define WS_PTS4  5668
#define WS_W1TH  38440              // u16 [112][224] bf16-hi of W1^T
#define WS_W1TL  50984              // u16 [112][224] bf16-lo
#define WS_W2TH  63528              // u16 [112][128] (K zero-padded)
#define WS_W2TL  70696
#define WS_WCT   77864              // f32 [20][112] Wc^T

typedef __attribute__((ext_vector_type(8))) short bf16x8;   // 8 bf16 = 4 VGPRs
typedef __attribute__((ext_vector_type(4))) float f32x4;
typedef unsigned short us;
typedef unsigned long long u64;

__device__ __forceinline__ float bf2f(us u) {
    union { unsigned int i; float f; } v; v.i = ((unsigned int)u) << 16; return v.f;
}
__device__ __forceinline__ us f2bf(float f) {
    union { float f; unsigned int i; } v; v.f = f;
    unsigned int r = v.i + 0x7fffu + ((v.i >> 16) & 1u);
    return (us)(r >> 16);
}
__device__ __forceinline__ void split(float v, us& h, us& l) {
    h = f2bf(v); l = f2bf(v - bf2f(h));
}

// sortable-u64 key: ascending u64 order == lex-(e asc, j asc)
__device__ __forceinline__ u64 mkkey(float e, int j) {
    union { float f; unsigned int i; } v; v.f = e;
    unsigned int ue = v.i ^ ((unsigned int)((int)v.i >> 31) | 0x80000000u);
    return ((u64)ue << 32) | (unsigned int)j;
}
__device__ __forceinline__ float keyval(u64 k) {
    unsigned int ue = (unsigned int)(k >> 32);
    unsigned int u = ue ^ ((unsigned int)((int)(~ue) >> 31) | 0x80000000u);
    union { unsigned int i; float f; } v; v.i = u; return v.f;
}
__device__ __forceinline__ u64 umin64(u64 a, u64 b) { return a < b ? a : b; }
__device__ __forceinline__ u64 umax64(u64 a, u64 b) { return a > b ? a : b; }

// ---- prep: pool (0..31) + grid build (32) + weight tables (33,34); 1024 threads
__global__ __launch_bounds__(PT) void k_prep(const float* __restrict__ cs,
                                             const float* __restrict__ fs7,
                                             const float* __restrict__ wat,
                                             const float* __restrict__ W1,
                                             const float* __restrict__ W2,
                                             const float* __restrict__ Wc,
                                             float* __restrict__ ws) {
    int b = blockIdx.x, tid = threadIdx.x;

    if (b == POOLB + 1) {           // W1^T bf16 hi/lo tables
        us* w1h = (us*)(ws + WS_W1TH);
        us* w1l = (us*)(ws + WS_W1TL);
        for (int idx = tid; idx < Cv * 224; idx += PT) {
            int c = idx / 224, k = idx - c * 224;
            us h, l; split(W1[k * Cv + c], h, l);
            w1h[c * 224 + k] = h; w1l[c * 224 + k] = l;
        }
        return;
    }
    if (b == POOLB + 2) {           // W2^T (K padded to 128) + Wc^T
        us* w2h = (us*)(ws + WS_W2TH);
        us* w2l = (us*)(ws + WS_W2TL);
        for (int idx = tid; idx < Cv * 128; idx += PT) {
            int c = idx >> 7, k = idx & 127;
            float v = (k < Cv) ? W2[k * Cv + c] : 0.f;
            us h, l; split(v, h, l);
            w2h[c * 128 + k] = h; w2l[c * 128 + k] = l;
        }
        float* wct = ws + WS_WCT;
        for (int idx = tid; idx < CLSv * Cv; idx += PT) {
            int cls = idx / Cv, k = idx - cls * Cv;
            wct[cls * Cv + k] = Wc[k * CLSv + cls];
        }
        return;
    }
    if (b == POOLB) {               // grid build: reg-cached coords, 2-barrier scan
        __shared__ int cnt[NCELL];
        __shared__ int wsum[PT / 64];
        us* startg = (us*)(ws + WS_START);
        float4* pts4 = (float4*)(ws + WS_PTS4);
        int lane = tid & 63, wv = tid >> 6;
        for (int i = tid; i < NCELL; i += PT) cnt[i] = 0;
        __syncthreads();
        float xx[8], yy[8], zz[8]; int cid[8]; int pp[8];
        #pragma unroll
        for (int k = 0; k < NSv / PT; ++k) {
            int p = k * PT + tid;
            pp[k] = p;
            xx[k] = cs[3 * p]; yy[k] = cs[3 * p + 1]; zz[k] = cs[3 * p + 2];
            int cx = (int)(xx[k] * INVH), cy = (int)(yy[k] * INVH), cz = (int)(zz[k] * INVH);
            cx = cx > 15 ? 15 : cx; cy = cy > 15 ? 15 : cy; cz = cz > 15 ? 15 : cz;
            cid[k] = (cz * GC + cy) * GC + cx;
            atomicAdd(&cnt[cid[k]], 1);
        }
        __syncthreads();
        int base = tid * 4;
        int c0 = cnt[base], c1 = cnt[base + 1], c2 = cnt[base + 2], c3 = cnt[base + 3];
        int local = c0 + c1 + c2 + c3;
        int inc = local;                           // wave inclusive scan
        #pragma unroll
        for (int off = 1; off < 64; off <<= 1) {
            int v = __shfl_up(inc, off, 64);
            if (lane >= off) inc += v;
        }
        if (lane == 63) wsum[wv] = inc;
        __syncthreads();
        if (tid < PT / 64) {                       // scan 16 wave totals (wave 0)
            int v = wsum[tid];
            #pragma unroll
            for (int off = 1; off < 16; off <<= 1) {
                int o = __shfl_up(v, off, 64);
                if (tid >= off) v += o;
            }
            wsum[tid] = v;
        }
        __syncthreads();
        int wbase = (wv == 0) ? 0 : wsum[wv - 1];
        int run = wbase + inc - local;             // exclusive prefix for this thread
        startg[base] = (us)run;     cnt[base] = run;     run += c0;
        startg[base + 1] = (us)run; cnt[base + 1] = run; run += c1;
        startg[base + 2] = (us)run; cnt[base + 2] = run; run += c2;
        startg[base + 3] = (us)run; cnt[base + 3] = run;
        if (tid == 0) startg[NCELL] = (us)NSv;
        __syncthreads();
        #pragma unroll
        for (int k = 0; k < NSv / PT; ++k) {
            int slot = atomicAdd(&cnt[cid[k]], 1);
            pts4[slot] = make_float4(-2.f * xx[k], -2.f * yy[k], -2.f * zz[k], (float)pp[k]);
        }
        return;
    }

    // pool partials: 512 waves total, 16 rows each; TRANSPOSED store [ch][b]
    __shared__ float red[PT / 64][Cv + 1];
    int gtid = b * PT + tid;
    int wid = gtid >> 6, lw = tid >> 6, lane = gtid & 63, l2 = lane * 2;
    float2 wa = make_float2(0.f, 0.f);
    if (lane < 56) wa = *(const float2*)(wat + l2);
    float gx = 0.f, gy = 0.f, z = 0.f;
    for (int g = 0; g < 2; ++g) {
        float2 f[8]; float part[8];
        #pragma unroll
        for (int u = 0; u < 8; ++u) {
            int i = wid + (g * 8 + u) * PNW;
            f[u] = (lane < 56) ? *(const float2*)(fs7 + i * Cv + l2) : make_float2(0.f, 0.f);
            part[u] = f[u].x * wa.x + f[u].y * wa.y;
        }
        #pragma unroll
        for (int off = 32; off; off >>= 1)
            #pragma unroll
            for (int u = 0; u < 8; ++u) part[u] += __shfl_xor(part[u], off, 64);
        #pragma unroll
        for (int u = 0; u < 8; ++u) {
            float p = __expf(part[u]);
            gx = fmaf(p, f[u].x, gx); gy = fmaf(p, f[u].y, gy); z += p;
        }
    }
    if (lane < 56) { red[lw][l2] = gx; red[lw][l2 + 1] = gy; }
    if (lane == 0) red[lw][Cv] = z;
    __syncthreads();
    if (tid < Cv + 1) {
        float s = 0.f;
        #pragma unroll
        for (int i = 0; i < PT / 64; ++i) s += red[i][tid];
        ws[tid * POOLB + b] = s;                   // transposed: row=channel, col=block
    }
}

// single-point lex-(e, idx) top-3 insert; canonical FMA chain for e
__device__ __forceinline__ void ins_pt(float4 P, float qx, float qy, float qz,
                                       float& E0, float& E1, float& E2,
                                       int& J0, int& J1, int& J2) {
    float x = -0.5f * P.x, y = -0.5f * P.y, z = -0.5f * P.z;
    float s2 = fmaf(x, x, fmaf(y, y, z * z));
    float e = fmaf(qx, P.x, fmaf(qy, P.y, fmaf(qz, P.z, s2)));
    int j = (int)P.w;
    bool lt2 = (e < E2) || (e == E2 && j < J2);
    if (lt2) {
        bool lt1 = (e < E1) || (e == E1 && j < J1);
        bool lt0 = (e < E0) || (e == E0 && j < J0);
        E2 = lt1 ? E1 : e;              J2 = lt1 ? J1 : j;
        E1 = lt0 ? E0 : (lt1 ? e : E1); J1 = lt0 ? J0 : (lt1 ? j : J1);
        if (lt0) { E0 = e; J0 = j; }
    }
}

// 2-wide point stream: both loads issue before the insert chain; order k,k+1 kept
__device__ __forceinline__ void scan_run(const float4* __restrict__ pts4,
                                         int a, int b, float qx, float qy, float qz,
                                         float& E0, float& E1, float& E2,
                                         int& J0, int& J1, int& J2) {
    int k = a;
    for (; k + 2 <= b; k += 2) {
        float4 P0 = pts4[k];
        float4 P1 = pts4[k + 1];
        ins_pt(P0, qx, qy, qz, E0, E1, E2, J0, J1, J2);
        ins_pt(P1, qx, qy, qz, E0, E1, E2, J0, J1, J2);
    }
    if (k < b) {
        float4 P0 = pts4[k];
        ins_pt(P0, qx, qy, qz, E0, E1, E2, J0, J1, J2);
    }
}

// ---- fused: in-block 16-lane-group kNN search + MFMA MLP. 512 threads, 32 q/block.
// Group-local V-build (no search->V barrier); gate synced by the pre-search barrier.
__global__ __launch_bounds__(MT, 6) void k_fused(
        const float* __restrict__ cq,
        const float* __restrict__ x7, const float* __restrict__ fs,
        const float* __restrict__ gma, const float* __restrict__ bta,
        const float* __restrict__ bc, const float* __restrict__ ws,
        float* __restrict__ out) {
    __shared__ __align__(16) us vb[2 * MQ * 232];   // [hi | lo], h2f aliases after GEMM1
    __shared__ __align__(16) us hbh[MQ * 136];      // h1 bf16-hi, K padded to 128
    __shared__ __align__(16) us hbl[MQ * 136];
    __shared__ float gate[Cv];

    us* vbh = vb;
    us* vbl = vb + MQ * 232;
    float* h2f = (float*)vb;                        // 32*116 f32 = 14848 B, fits

    const us* __restrict__ startg = (const us*)(ws + WS_START);
    const float4* __restrict__ pts4 = (const float4*)(ws + WS_PTS4);

    int tid = threadIdx.x;
    int q0 = blockIdx.x * MQ;
    int sub = tid & 15;
    int qq  = tid >> 4;                          // 0..31: this thread's query group
    int q   = q0 + qq;

    // x7 prefetch only (gate comes from LDS at use time; avoids register spill)
    float4 px[4];
    if (sub < 7) {
        const float4* xr = (const float4*)(x7 + q * Cv + sub * 16);
        px[0] = xr[0]; px[1] = xr[1]; px[2] = xr[2]; px[3] = xr[3];
    }

    if (tid < Cv) {                              // gate = sigmoid(pooled mean), coalesced
        float st = 0.f, zt = 0.f;
        const float* pr = ws + tid * POOLB;
        const float* zr = ws + Cv * POOLB;
        #pragma unroll
        for (int b = 0; b < POOLB; ++b) { st += pr[b]; zt += zr[b]; }
        gate[tid] = 1.0f / (1.0f + __expf(-(st / zt)));
    }
    {                                            // zero h1 K-pad (k=112..127)
        int zq = tid >> 4, kk = Cv + (tid & 15);
        hbh[zq * 136 + kk] = 0; hbl[zq * 136 + kk] = 0;
    }
    __syncthreads();                             // gate + K-pad visible to everyone

    // ---- search phase: 32 groups of 16 lanes, one query each
    u64 K0 = ~0ull, K1 = ~0ull, K2 = ~0ull;
    {
        float qx = cq[3 * q], qy = cq[3 * q + 1], qz = cq[3 * q + 2];
        float q2 = fmaf(qx, qx, fmaf(qy, qy, qz * qz));
        int cx = (int)(qx * INVH), cy = (int)(qy * INVH), cz = (int)(qz * INVH);
        cx = cx > 15 ? 15 : cx; cy = cy > 15 ? 15 : cy; cz = cz > 15 ? 15 : cz;
        float E0 = INFF, E1 = INFF, E2 = INFF;
        int   J0 = JINF, J1 = JINF, J2 = JINF;

        #pragma unroll
        for (int c = sub; c < 27; c += 16) {     // 3x3x3 core, 16 lanes
            int dz = c / 9 - 1, dy = (c / 3) % 3 - 1, dx = c % 3 - 1;
            int xc = cx + dx, yc = cy + dy, zc = cz + dz;
            if ((unsigned)xc < 16u && (unsigned)yc < 16u && (unsigned)zc < 16u) {
                int ccell = (zc * GC + yc) * GC + xc;
                scan_run(pts4, startg[ccell], startg[ccell + 1], qx, qy, qz,
                         E0, E1, E2, J0, J1, J2);
            }
        }

        bool done = false;
        for (int s = 2; ; ++s) {
            if (!done) {                         // 16-lane merge butterfly (4 steps)
                K0 = mkkey(E0, J0); K1 = mkkey(E1, J1); K2 = mkkey(E2, J2);
                #pragma unroll
                for (int off = 1; off < 16; off <<= 1) {
                    u64 b0 = __shfl_xor(K0, off, 64);
                    u64 b1 = __shfl_xor(K1, off, 64);
                    u64 b2 = __shfl_xor(K2, off, 64);
                    u64 xx = umax64(K0, b0), yy = umin64(K1, b1);
                    u64 zz = umax64(K1, b1), uu = umin64(K2, b2);
                    K0 = umin64(K0, b0);
                    u64 n1 = umin64(xx, yy);
                    K2 = umin64(umin64(umax64(xx, yy), zz), uu);
                    K1 = n1;
                }
            }
            if (s > 15) break;
            if (!done) {
                int r = s - 1;
                int xl = cx - r > 0 ? cx - r : 0, xh = cx + r < 15 ? cx + r : 15;
                int yl = cy - r > 0 ? cy - r : 0, yh = cy + r < 15 ? cy + r : 15;
                int zl = cz - r > 0 ? cz - r : 0, zh = cz + r < 15 ? cz + r : 15;
                float fx = INFF, fy = INFF, fz = INFF;
                if (xl > 0)  fx = qx - xl * CELLH;
                if (xh < 15) fx = fminf(fx, (xh + 1) * CELLH - qx);
                if (yl > 0)  fy = qy - yl * CELLH;
                if (yh < 15) fy = fminf(fy, (yh + 1) * CELLH - qy);
                if (zl > 0)  fz = qz - zl * CELLH;
                if (zh < 15) fz = fminf(fz, (zh + 1) * CELLH - qz);
                float dmin = fminf(fx, fminf(fy, fz));
                float t2 = keyval(K2);
                if (dmin * dmin > t2 + q2 + 0.5f) {
                    done = true;
                } else if (s == 2) {             // specialized: compile-time divides
                    for (int idx = sub; idx < 125; idx += 16) {
                        int dz = idx / 25 - 2;
                        int rem = idx - (dz + 2) * 25;
                        int dy = rem / 5 - 2;
                        int dx = rem - (dy + 2) * 5 - 2;
                        int ax = dx < 0 ? -dx : dx, ay = dy < 0 ? -dy : dy, az = dz < 0 ? -dz : dz;
                        if (ax != 2 && ay != 2 && az != 2) continue;
                        int xc = cx + dx, yc = cy + dy, zc = cz + dz;
                        if ((unsigned)xc > 15u || (unsigned)yc > 15u || (unsigned)zc > 15u) continue;
                        int ccell = (zc * GC + yc) * GC + xc;
                        scan_run(pts4, startg[ccell], startg[ccell + 1], qx, qy, qz,
                                 E0, E1, E2, J0, J1, J2);
                    }
                } else {
                    int side = 2 * s + 1, s2n = side * side, tot = s2n * side;
                    for (int idx = sub; idx < tot; idx += 16) {
                        int dz = idx / s2n - s;
                        int rem = idx - (dz + s) * s2n;
                        int dy = rem / side - s;
                        int dx = rem - (dy + s) * side - s;
                        int ax = dx < 0 ? -dx : dx, ay = dy < 0 ? -dy : dy, az = dz < 0 ? -dz : dz;
                        if (ax != s && ay != s && az != s) continue;
                        int xc = cx + dx, yc = cy + dy, zc = cz + dz;
                        if ((unsigned)xc > 15u || (unsigned)yc > 15u || (unsigned)zc > 15u) continue;
                        int ccell = (zc * GC + yc) * GC + xc;
                        scan_run(pts4, startg[ccell], startg[ccell + 1], qx, qy, qz,
                                 E0, E1, E2, J0, J1, J2);
                    }
                }
            }
            if (__all(done)) break;
        }
    }

    // ---- group-local V build (no barrier: gate was synced pre-search; all lanes
    //      hold final K0..K2 for their own query)
    {
        unsigned int A0 = (unsigned int)K0;
        unsigned int A1 = (unsigned int)K1;
        unsigned int A2 = (unsigned int)K2;
        if (A0 >= NSv) A0 = 0;
        if (A1 >= NSv) A1 = 0;
        if (A2 >= NSv) A2 = 0;
        if (sub < 7) {                           // gated x7 half: cols sub*16..+16
            int k0 = sub * 16;
            const float4* g4 = (const float4*)(gate + k0);
            float vals[16];
            #pragma unroll
            for (int i = 0; i < 4; ++i) {
                float4 v = px[i], g = g4[i];
                vals[i * 4]     = v.x * g.x;
                vals[i * 4 + 1] = v.y * g.y;
                vals[i * 4 + 2] = v.z * g.z;
                vals[i * 4 + 3] = v.w * g.w;
            }
            #pragma unroll
            for (int i = 0; i < 16; ++i) {
                us h, l; split(vals[i], h, l);
                vbh[qq * 232 + k0 + i] = h;
                vbl[qq * 232 + k0 + i] = l;
            }
        } else if (sub < 14) {                   // matched half: cols 112+kk..+16
            float e0 = keyval(K0), e1 = keyval(K1), e2 = keyval(K2);
            float w1v = __expf(e0 - e1);
            float w2v = __expf(e0 - e2);
            float iw  = 1.0f / (1.0f + w1v + w2v);
            float w0 = iw, w1 = w1v * iw, w2 = w2v * iw;
            int kk = (sub - 7) * 16;
            const float4* r0 = (const float4*)(fs + A0 * Cv + kk);
            const float4* r1 = (const float4*)(fs + A1 * Cv + kk);
            const float4* r2 = (const float4*)(fs + A2 * Cv + kk);
            float vals[16];
            #pragma unroll
            for (int i = 0; i < 4; ++i) {
                float4 a = r0[i], b = r1[i], c = r2[i];
                vals[i * 4]     = w0 * a.x + w1 * b.x + w2 * c.x;
                vals[i * 4 + 1] = w0 * a.y + w1 * b.y + w2 * c.y;
                vals[i * 4 + 2] = w0 * a.z + w1 * b.z + w2 * c.z;
                vals[i * 4 + 3] = w0 * a.w + w1 * b.w + w2 * c.w;
            }
            int k0 = Cv + kk;
            #pragma unroll
            for (int i = 0; i < 16; ++i) {
                us h, l; split(vals[i], h, l);
                vbh[qq * 232 + k0 + i] = h;
                vbl[qq * 232 + k0 + i] = l;
            }
        }
    }
    __syncthreads();

    int w = tid >> 6, lane = tid & 63, quad = lane >> 4, l16 = lane & 15;
    int cc = (w < 7 ? w : 0) * 16 + l16;         // wave 7 idles through GEMMs

    // GEMM1: h1 = V @ W1  (K=224, 7 ksteps, 3 MFMA terms each, 2 M-tiles)
    if (w < 7) {
        f32x4 acc0 = {0.f, 0.f, 0.f, 0.f};
        f32x4 acc1 = {0.f, 0.f, 0.f, 0.f};
        const us* w1h = (const us*)(ws + WS_W1TH) + cc * 224;
        const us* w1l = (const us*)(ws + WS_W1TL) + cc * 224;
        #pragma unroll
        for (int ks = 0; ks < 7; ++ks) {
            int ko = ks * 32 + quad * 8;
            bf16x8 bh  = *(const bf16x8*)(w1h + ko);
            bf16x8 bl  = *(const bf16x8*)(w1l + ko);
            bf16x8 a0h = *(const bf16x8*)(vbh + l16 * 232 + ko);
            bf16x8 a0l = *(const bf16x8*)(vbl + l16 * 232 + ko);
            bf16x8 a1h = *(const bf16x8*)(vbh + (l16 + 16) * 232 + ko);
            bf16x8 a1l = *(const bf16x8*)(vbl + (l16 + 16) * 232 + ko);
            acc0 = __builtin_amdgcn_mfma_f32_16x16x32_bf16(a0h, bh, acc0, 0, 0, 0);
            acc0 = __builtin_amdgcn_mfma_f32_16x16x32_bf16(a0l, bh, acc0, 0, 0, 0);
            acc0 = __builtin_amdgcn_mfma_f32_16x16x32_bf16(a0h, bl, acc0, 0, 0, 0);
            acc1 = __builtin_amdgcn_mfma_f32_16x16x32_bf16(a1h, bh, acc1, 0, 0, 0);
            acc1 = __builtin_amdgcn_mfma_f32_16x16x32_bf16(a1l, bh, acc1, 0, 0, 0);
            acc1 = __builtin_amdgcn_mfma_f32_16x16x32_bf16(a1h, bl, acc1, 0, 0, 0);
        }
        float g = gma[cc], bb = bta[cc];
        #pragma unroll
        for (int r = 0; r < 4; ++r) {            // D row = quad*4+r, col = cc
            int dq = quad * 4 + r;
            float h = fmaf(acc0[r], g, bb); h = h > 0.f ? h : 0.f;
            us hh, ll; split(h, hh, ll);
            hbh[dq * 136 + cc] = hh; hbl[dq * 136 + cc] = ll;
            float h2 = fmaf(acc1[r], g, bb); h2 = h2 > 0.f ? h2 : 0.f;
            split(h2, hh, ll);
            hbh[(dq + 16) * 136 + cc] = hh; hbl[(dq + 16) * 136 + cc] = ll;
        }
    }
    __syncthreads();

    // GEMM2: h2 = h1 @ W2  (K=128 padded, 4 ksteps); h2f overwrites dead V region
    if (w < 7) {
        f32x4 acc0 = {0.f, 0.f, 0.f, 0.f};
        f32x4 acc1 = {0.f, 0.f, 0.f, 0.f};
        const us* w2h = (const us*)(ws + WS_W2TH) + cc * 128;
        const us* w2l = (const us*)(ws + WS_W2TL) + cc * 128;
        #pragma unroll
        for (int ks = 0; ks < 4; ++ks) {
            int ko = ks * 32 + quad * 8;
            bf16x8 bh  = *(const bf16x8*)(w2h + ko);
            bf16x8 bl  = *(const bf16x8*)(w2l + ko);
            bf16x8 a0h = *(const bf16x8*)(hbh + l16 * 136 + ko);
            bf16x8 a0l = *(const bf16x8*)(hbl + l16 * 136 + ko);
            bf16x8 a1h = *(const bf16x8*)(hbh + (l16 + 16) * 136 + ko);
            bf16x8 a1l = *(const bf16x8*)(hbl + (l16 + 16) * 136 + ko);
            acc0 = __builtin_amdgcn_mfma_f32_16x16x32_bf16(a0h, bh, acc0, 0, 0, 0);
            acc0 = __builtin_amdgcn_mfma_f32_16x16x32_bf16(a0l, bh, acc0, 0, 0, 0);
            acc0 = __builtin_amdgcn_mfma_f32_16x16x32_bf16(a0h, bl, acc0, 0, 0, 0);
            acc1 = __builtin_amdgcn_mfma_f32_16x16x32_bf16(a1h, bh, acc1, 0, 0, 0);
            acc1 = __builtin_amdgcn_mfma_f32_16x16x32_bf16(a1l, bh, acc1, 0, 0, 0);
            acc1 = __builtin_amdgcn_mfma_f32_16x16x32_bf16(a1h, bl, acc1, 0, 0, 0);
        }
        #pragma unroll
        for (int r = 0; r < 4; ++r) {
            int dq = quad * 4 + r;
            h2f[dq * 116 + cc] = acc0[r];
            h2f[(dq + 16) * 116 + cc] = acc1[r];
        }
    }
    __syncthreads();

    // classifier: out = h2 @ Wc + bc (f32 VALU, WcT rows contiguous)
    for (int it = tid; it < MQ * CLSv; it += MT) {
        int cls = it % CLSv, oq = it / CLSv;
        const float4* wr = (const float4*)(ws + WS_WCT + cls * Cv);
        const float4* hr = (const float4*)(h2f + oq * 116);
        float a = bc[cls];
        #pragma unroll 7
        for (int i = 0; i < 28; ++i) {
            float4 h = hr[i], v = wr[i];
            a = fmaf(h.x, v.x, fmaf(h.y, v.y, fmaf(h.z, v.z, fmaf(h.w, v.w, a))));
        }
        out[(q0 + oq) * CLSv + cls] = a;
    }
}

extern "C" void kernel_launch(void* const* d_in, const int* in_sizes, int n_in,
                              void* d_out, int out_size, void* d_ws, size_t ws_size,
                              hipStream_t stream) {
    const float* cq  = (const float*)d_in[0];
    const float* cs  = (const float*)d_in[1];
    const float* x7  = (const float*)d_in[2];
    const float* fs7 = (const float*)d_in[3];
    const float* fs  = (const float*)d_in[4];
    const float* wat = (const float*)d_in[5];
    const float* W1  = (const float*)d_in[6];
    const float* gma = (const float*)d_in[7];
    const float* bta = (const float*)d_in[8];
    const float* W2  = (const float*)d_in[9];
    const float* Wc  = (const float*)d_in[10];
    const float* bc  = (const float*)d_in[11];
    float* ws  = (float*)d_ws;
    float* out = (float*)d_out;

    k_prep<<<POOLB + 3, PT, 0, stream>>>(cs, fs7, wat, W1, W2, Wc, ws);
    k_fused<<<MB, MT, 0, stream>>>(cq, x7, fs, gma, bta, bc, ws, out);
}